// Round 1
// baseline (167.469 us; speedup 1.0000x reference)
//
#include <hip/hip_runtime.h>
#include <math.h>

#define DIM 64
#define NNB 16
#define BATCH 16384

template <int WPB>
__global__ __launch_bounds__(WPB * 64) void klgcn_kernel(
    const int* __restrict__ u, const int* __restrict__ v,
    const int* __restrict__ user_neighbor, const int* __restrict__ item_neighbor,
    const int* __restrict__ adj_ent, const int* __restrict__ adj_rel,
    const float* __restrict__ usr_emb, const float* __restrict__ ent_emb,
    const float* __restrict__ rel_emb, const float* __restrict__ agg_W,
    const float* __restrict__ agg_b, float* __restrict__ out)
{
    const int wave = threadIdx.x >> 6;
    const int lane = threadIdx.x & 63;
    const int b = blockIdx.x * WPB + wave;
    if (b >= BATCH) return;

    __shared__ float comb_lds[WPB][DIM];

    const int ub = u[b];
    const int vb = v[b];

    // lite_user = mean_n usr_emb[item_neighbor[b][n]]   (lane = dim)
    float lite_user = 0.f;
#pragma unroll
    for (int n = 0; n < NNB; n++) {
        const int idx = item_neighbor[b * NNB + n];
        lite_user += usr_emb[(long)idx * DIM + lane];
    }
    lite_user *= (1.0f / NNB);

    // lite_item = mean_n ent_emb[user_neighbor[b][n]]
    float lite_item = 0.f;
#pragma unroll
    for (int n = 0; n < NNB; n++) {
        const int idx = user_neighbor[b * NNB + n];
        lite_item += ent_emb[(long)idx * DIM + lane];
    }
    lite_item *= (1.0f / NNB);

    const float ue = usr_emb[(long)ub * DIM + lane];
    const float ie = ent_emb[(long)vb * DIM + lane];

    // attention scores: ur_scores[n] = dot(ue, rel_emb[adj_rel[v][n]])
    float attn[NNB];
#pragma unroll
    for (int n = 0; n < NNB; n++) {
        const int r = adj_rel[vb * NNB + n];
        float p = ue * rel_emb[r * DIM + lane];
#pragma unroll
        for (int s = 32; s > 0; s >>= 1) p += __shfl_xor(p, s, 64);
        attn[n] = p;  // full dot, present in all lanes
    }

    // softmax over the 16 scores (redundant per lane, registers only)
    float m = attn[0];
#pragma unroll
    for (int n = 1; n < NNB; n++) m = fmaxf(m, attn[n]);
    float ssum = 0.f;
#pragma unroll
    for (int n = 0; n < NNB; n++) {
        attn[n] = __expf(attn[n] - m);
        ssum += attn[n];
    }
    const float inv = 1.0f / ssum;

    // neighbors_agg[d] = sum_n attn[n] * ent_emb[adj_ent[v][n]][d]
    float agg = 0.f;
#pragma unroll
    for (int n = 0; n < NNB; n++) {
        const int e = adj_ent[vb * NNB + n];
        agg += attn[n] * ent_emb[(long)e * DIM + lane];
    }
    agg *= inv;

    // combined -> LDS for the 64x64 matvec broadcast
    const float combined = ie + agg;
    comb_lds[wave][lane] = combined;
    // wave-local LDS write->read: lockstep wave + compiler lgkmcnt; no barrier needed

    float acc = agg_b[lane];
#pragma unroll
    for (int d = 0; d < DIM; d++) {
        acc = fmaf(comb_lds[wave][d], agg_W[d * DIM + lane], acc);
    }
    const float item_emb = tanhf(acc);

    const float uf = 0.5f * (lite_user + ue);
    const float itf = 0.5f * (lite_item + item_emb);

    float p = uf * itf;
#pragma unroll
    for (int s = 32; s > 0; s >>= 1) p += __shfl_xor(p, s, 64);

    if (lane == 0) out[b] = 1.0f / (1.0f + __expf(-p));
}

extern "C" void kernel_launch(void* const* d_in, const int* in_sizes, int n_in,
                              void* d_out, int out_size, void* d_ws, size_t ws_size,
                              hipStream_t stream)
{
    const int*   u             = (const int*)d_in[0];
    const int*   v             = (const int*)d_in[1];
    const int*   user_neighbor = (const int*)d_in[2];
    const int*   item_neighbor = (const int*)d_in[3];
    const int*   adj_ent       = (const int*)d_in[4];
    const int*   adj_rel       = (const int*)d_in[5];
    const float* usr_emb       = (const float*)d_in[6];
    const float* ent_emb       = (const float*)d_in[7];
    const float* rel_emb       = (const float*)d_in[8];
    const float* agg_W         = (const float*)d_in[9];
    const float* agg_b         = (const float*)d_in[10];
    float* out = (float*)d_out;

    constexpr int WPB = 4;  // 4 waves/block, one batch element per wave
    dim3 grid(BATCH / WPB), block(WPB * 64);
    klgcn_kernel<WPB><<<grid, block, 0, stream>>>(
        u, v, user_neighbor, item_neighbor, adj_ent, adj_rel,
        usr_emb, ent_emb, rel_emb, agg_W, agg_b, out);
}

// Round 2
// 151.249 us; speedup vs baseline: 1.1072x; 1.1072x over previous
//
#include <hip/hip_runtime.h>
#include <math.h>

#define DIM 64
#define NNB 16
#define BATCH 16384

template <int WPB>
__global__ __launch_bounds__(WPB * 64, 2) void klgcn_kernel(
    const int* __restrict__ u, const int* __restrict__ v,
    const int* __restrict__ user_neighbor, const int* __restrict__ item_neighbor,
    const int* __restrict__ adj_ent, const int* __restrict__ adj_rel,
    const float* __restrict__ usr_emb, const float* __restrict__ ent_emb,
    const float* __restrict__ rel_emb, const float* __restrict__ agg_W,
    const float* __restrict__ agg_b, float* __restrict__ out)
{
    const int wave = threadIdx.x >> 6;
    const int lane = threadIdx.x & 63;
    int b = blockIdx.x * WPB + wave;
    b = __builtin_amdgcn_readfirstlane(b);

    __shared__ float comb_lds[WPB][DIM];

    // Wave-uniform scalars: force onto the scalar path.
    const int ub = __builtin_amdgcn_readfirstlane(u[b]);
    const int vb = __builtin_amdgcn_readfirstlane(v[b]);

    // Issue the two direct rows first.
    const float ue = usr_emb[(long)ub * DIM + lane];
    const float ie = ent_emb[(long)vb * DIM + lane];

    // All 64 indices, wave-uniform -> scalar regs.
    int i_it[NNB], i_un[NNB], i_ar[NNB], i_ae[NNB];
#pragma unroll
    for (int n = 0; n < NNB; n++)
        i_it[n] = __builtin_amdgcn_readfirstlane(item_neighbor[b * NNB + n]);
#pragma unroll
    for (int n = 0; n < NNB; n++)
        i_un[n] = __builtin_amdgcn_readfirstlane(user_neighbor[b * NNB + n]);
#pragma unroll
    for (int n = 0; n < NNB; n++)
        i_ar[n] = __builtin_amdgcn_readfirstlane(adj_rel[vb * NNB + n]);
#pragma unroll
    for (int n = 0; n < NNB; n++)
        i_ae[n] = __builtin_amdgcn_readfirstlane(adj_ent[vb * NNB + n]);

    // ---- Phase 1: issue ALL independent gathers (64 outstanding loads/lane).
    // Issue order == consumption order (FIFO vmcnt-friendly).
    float r_lu[NNB], r_li[NNB], r_re[NNB], r_ag[NNB];
#pragma unroll
    for (int n = 0; n < NNB; n++) r_lu[n] = usr_emb[(long)i_it[n] * DIM + lane];
#pragma unroll
    for (int n = 0; n < NNB; n++) r_li[n] = ent_emb[(long)i_un[n] * DIM + lane];
#pragma unroll
    for (int n = 0; n < NNB; n++) r_re[n] = rel_emb[i_ar[n] * DIM + lane];
#pragma unroll
    for (int n = 0; n < NNB; n++) r_ag[n] = ent_emb[(long)i_ae[n] * DIM + lane];

    // ---- Phase 2: consume.
    float lite_user = 0.f;
#pragma unroll
    for (int n = 0; n < NNB; n++) lite_user += r_lu[n];
    lite_user *= (1.0f / NNB);

    float lite_item = 0.f;
#pragma unroll
    for (int n = 0; n < NNB; n++) lite_item += r_li[n];
    lite_item *= (1.0f / NNB);

    // attention scores: ur_scores[n] = dot(ue, rel_emb[adj_rel[v][n]])
    float attn[NNB];
#pragma unroll
    for (int n = 0; n < NNB; n++) {
        float p = ue * r_re[n];
#pragma unroll
        for (int s = 32; s > 0; s >>= 1) p += __shfl_xor(p, s, 64);
        attn[n] = p;  // full dot, present in all lanes
    }

    // softmax over the 16 scores (redundant per lane, registers only)
    float m = attn[0];
#pragma unroll
    for (int n = 1; n < NNB; n++) m = fmaxf(m, attn[n]);
    float ssum = 0.f;
#pragma unroll
    for (int n = 0; n < NNB; n++) {
        attn[n] = __expf(attn[n] - m);
        ssum += attn[n];
    }
    const float inv = 1.0f / ssum;

    // neighbors_agg[d] = sum_n attn[n] * ent_emb[adj_ent[v][n]][d]
    float agg = 0.f;
#pragma unroll
    for (int n = 0; n < NNB; n++) agg += attn[n] * r_ag[n];
    agg *= inv;

    // combined -> LDS for the 64x64 matvec broadcast
    const float combined = ie + agg;
    comb_lds[wave][lane] = combined;
    // wave-local LDS write->read: lockstep wave + compiler lgkmcnt; no barrier needed

    float acc = agg_b[lane];
#pragma unroll
    for (int d = 0; d < DIM; d++) {
        acc = fmaf(comb_lds[wave][d], agg_W[d * DIM + lane], acc);
    }
    const float item_emb = tanhf(acc);

    const float uf = 0.5f * (lite_user + ue);
    const float itf = 0.5f * (lite_item + item_emb);

    float p = uf * itf;
#pragma unroll
    for (int s = 32; s > 0; s >>= 1) p += __shfl_xor(p, s, 64);

    if (lane == 0) out[b] = 1.0f / (1.0f + __expf(-p));
}

extern "C" void kernel_launch(void* const* d_in, const int* in_sizes, int n_in,
                              void* d_out, int out_size, void* d_ws, size_t ws_size,
                              hipStream_t stream)
{
    const int*   u             = (const int*)d_in[0];
    const int*   v             = (const int*)d_in[1];
    const int*   user_neighbor = (const int*)d_in[2];
    const int*   item_neighbor = (const int*)d_in[3];
    const int*   adj_ent       = (const int*)d_in[4];
    const int*   adj_rel       = (const int*)d_in[5];
    const float* usr_emb       = (const float*)d_in[6];
    const float* ent_emb       = (const float*)d_in[7];
    const float* rel_emb       = (const float*)d_in[8];
    const float* agg_W         = (const float*)d_in[9];
    const float* agg_b         = (const float*)d_in[10];
    float* out = (float*)d_out;

    constexpr int WPB = 4;  // 4 waves/block, one batch element per wave
    dim3 grid(BATCH / WPB), block(WPB * 64);
    klgcn_kernel<WPB><<<grid, block, 0, stream>>>(
        u, v, user_neighbor, item_neighbor, adj_ent, adj_rel,
        usr_emb, ent_emb, rel_emb, agg_W, agg_b, out);
}